// Round 11
// baseline (504.707 us; speedup 1.0000x reference)
//
#include <hip/hip_runtime.h>

#define NB 256
#define NT 4096
#define CH 128
#define NCHUNK (NT / CH)

typedef unsigned int u32;
typedef unsigned long long u64;
typedef int v2i __attribute__((ext_vector_type(2)));

typedef __attribute__((address_space(1))) const u32 gas_u32;
typedef __attribute__((address_space(3))) u32 las_u32;

__device__ __forceinline__ void gll16(const void* g, void* l) {
  __builtin_amdgcn_global_load_lds((gas_u32*)g, (las_u32*)l, 16, 0, 0);
}

template <int CTRL>
__device__ __forceinline__ float dppf(float x) {
  return __int_as_float(__builtin_amdgcn_update_dpp(
      0, __float_as_int(x), CTRL, 0xF, 0xF, true));
}

__device__ __forceinline__ float pl16max(float x) {
#if __has_builtin(__builtin_amdgcn_permlane16_swap)
  v2i r = __builtin_amdgcn_permlane16_swap(__float_as_int(x), __float_as_int(x),
                                           false, false);
  return fmaxf(__int_as_float(r[0]), __int_as_float(r[1]));
#else
  return fmaxf(x, __shfl_xor(x, 16, 64));
#endif
}

__device__ __forceinline__ float pl32max(float x) {
#if __has_builtin(__builtin_amdgcn_permlane32_swap)
  v2i r = __builtin_amdgcn_permlane32_swap(__float_as_int(x), __float_as_int(x),
                                           false, false);
  return fmaxf(__int_as_float(r[0]), __int_as_float(r[1]));
#else
  return fmaxf(x, __shfl_xor(x, 32, 64));
#endif
}

__global__ void __launch_bounds__(64, 1)
viterbi_k(const float* __restrict__ feats, const float* __restrict__ trans,
          float* __restrict__ out) {
  // LDS: 36864 + 6144 + 16640 + 4096 = 63744 B (< 64KB)
  __shared__ __align__(16) float s_tr[2 * CH * 36];
  __shared__ __align__(16) float s_ft[2 * CH * 6];
  __shared__ u32 s_psi[64 * 65];   // padded stride 65: conflict-free column reads
  __shared__ u32 s_path[NT / 4];

  const int b = blockIdx.x;
  const int lane = (int)threadIdx.x;
  const int g = lane >> 3;        // group index
  const int l = lane & 7;         // in-group index
  const int gg = (g < 6) ? g : 5; // clamp -> duplicate-of-5 invariant
  const int jj = (l < 6) ? l : 5;
  // A-step (odd t): roles i=g, j=l; B-step (even t): roles i=l, j=g
  const int offTA = gg * 6 + jj;   // trans[t][i=g][j=l]
  const int offTB = jj * 6 + gg;   // trans[t][i=l][j=g]
  const int offFA = gg;            // feat[t][i=g]
  const int offFB = jj;            // feat[t][i=l]

  const float* trb = trans + (size_t)b * NT * 36;
  const float* ftb = feats + (size_t)b * NT * 6;

  // layout0: lane (g,l) holds delta[jj] — lanes l>=6 duplicate state 5.
  float delta = (l == 4) ? 0.0f : -10000.0f;

  auto stage = [&](int c) {
    const int buf = c & 1;
    const float* gt = trb + (size_t)c * CH * 36;
    float* lt = s_tr + buf * (CH * 36);
#pragma unroll
    for (int i = 0; i < 18; ++i) gll16(gt + i * 256 + lane * 4, lt + i * 256);
    const float* gf = ftb + (size_t)c * CH * 6;
    float* lf = s_ft + buf * (CH * 6);
#pragma unroll
    for (int i = 0; i < 3; ++i) gll16(gf + i * 256 + lane * 4, lf + i * 256);
  };

  // consumes layout0, produces layout1 (lane (g,l) -> delta_new[g])
  auto stepA = [&](float tr, float ft) -> u64 {
    float s = tr + delta;                   // exact: same single add as ref
    float m = fmaxf(s, dppf<0xB1>(s));      // xor1
    m = fmaxf(m, dppf<0x4E>(m));            // xor2
    m = fmaxf(m, dppf<0x141>(m));           // xor4 via row_half_mirror
    u64 bal = __ballot(s == m);             // bits at 8i+j (uniform, SGPRs)
    delta = m + ft;
    return bal;
  };

  // consumes layout1, produces layout0 (lane (g,l) -> delta_new[l])
  auto stepB = [&](float tr, float ft) -> u64 {
    float s = tr + delta;
    float m = fmaxf(s, dppf<0x128>(s));     // xor8 (row_ror:8)
    m = pl16max(m);                         // xor16
    m = pl32max(m);                         // xor32
    u64 bal = __ballot(s == m);             // bits at 8j+i (uniform)
    delta = m + ft;
    return bal;
  };

  // Scalar (SALU) psi unpack + single-lane LDS store — off the VALU chain.
  // Fields are provably non-empty: duplicate lanes mirror state 5, so the
  // j<6 mask always contains a winner; ctz = smallest index (ref tie-break).
  auto psiA = [&](u64 bal, u32* pq) {       // A: psi_i = ctz((bal>>8i)&63)
    u32 lo = (u32)bal, hi = (u32)(bal >> 32);
    u32 p = (u32)__builtin_ctz(lo & 63u);
    p |= (u32)__builtin_ctz((lo >> 8) & 63u) << 3;
    p |= (u32)__builtin_ctz((lo >> 16) & 63u) << 6;
    p |= (u32)__builtin_ctz((lo >> 24) & 63u) << 9;
    p |= (u32)__builtin_ctz(hi & 63u) << 12;
    p |= (u32)__builtin_ctz((hi >> 8) & 63u) << 15;
    if (lane == 0) *pq = p;
  };
  auto psiB = [&](u64 bal, u32* pq) {       // B: bits for state i at 8j+i
    u32 p = 0;
#pragma unroll
    for (int i = 0; i < 6; ++i) {
      u64 mm = (bal >> i) & 0x0000010101010101ULL;
      p |= ((u32)(__builtin_ctzll(mm) >> 3)) << (3 * i);
    }
    if (lane == 0) *pq = p;
  };

#define LOAD8(trv, ftv, g8base)                                               \
  {                                                                           \
    _Pragma("unroll") for (int q = 0; q < 8; ++q) {                           \
      trv[q] = trp[((g8base) + q) * 36 + ((q & 1) ? offTA : offTB)];          \
      ftv[q] = ftp[((g8base) + q) * 6 + ((q & 1) ? offFA : offFB)];           \
    }                                                                         \
  }

// 8 steps + psi store, with next group's loads interleaved
#define STEPS8L(trv, ftv, PQ, ntr, nft, ng8)                                  \
  {                                                                           \
    _Pragma("unroll") for (int q = 0; q < 8; ++q) {                           \
      if (q & 1) psiA(stepA(trv[q], ftv[q]), (PQ) + q);                       \
      else       psiB(stepB(trv[q], ftv[q]), (PQ) + q);                       \
      ntr[q] = trp[((ng8) + q) * 36 + ((q & 1) ? offTA : offTB)];             \
      nft[q] = ftp[((ng8) + q) * 6 + ((q & 1) ? offFA : offFB)];              \
    }                                                                         \
  }

#define STEPS8(trv, ftv, PQ)                                                  \
  {                                                                           \
    _Pragma("unroll") for (int q = 0; q < 8; ++q) {                           \
      if (q & 1) psiA(stepA(trv[q], ftv[q]), (PQ) + q);                       \
      else       psiB(stepB(trv[q], ftv[q]), (PQ) + q);                       \
    }                                                                         \
  }

  stage(0);
  asm volatile("s_waitcnt vmcnt(0)" ::: "memory");
  stage(1);

  // ---- chunk 0 (t = 1..127; t=0 skipped). t odd -> stepA, t even -> stepB.
  {
    const float* trp = s_tr;
    const float* ftp = s_ft;
    float trA[8], ftA[8], trB[8], ftB[8];
    LOAD8(trA, ftA, 0);
    LOAD8(trB, ftB, 8);
    if (lane == 0) s_psi[0] = 0x36DB6u;   // dummy psi for t=0 (fields=6)
#pragma unroll
    for (int q = 1; q < 8; ++q) {
      if (q & 1) psiA(stepA(trA[q], ftA[q]), s_psi + q);
      else       psiB(stepB(trA[q], ftA[q]), s_psi + q);
    }
    LOAD8(trA, ftA, 16);
    STEPS8(trB, ftB, s_psi + 8);
#pragma unroll 1
    for (int g2 = 2; g2 < 14; g2 += 2) {
      u32* pqa = s_psi + ((g2 & 8) ? 65 : 0) + ((g2 * 8) & 63);
      STEPS8L(trA, ftA, pqa, trB, ftB, (g2 + 1) * 8);
      u32* pqb = s_psi + (((g2 + 1) & 8) ? 65 : 0) + (((g2 + 1) * 8) & 63);
      STEPS8L(trB, ftB, pqb, trA, ftA, (g2 + 2) * 8);
    }
    // peeled groups 14,15 (window 1 of this chunk)
    STEPS8L(trA, ftA, s_psi + 65 + 48, trB, ftB, 120);
    STEPS8(trB, ftB, s_psi + 65 + 56);
  }

  // ---- chunks 1..31 (tbase even => t parity == q parity)
#pragma unroll 1
  for (int c = 1; c < NCHUNK; ++c) {
    asm volatile("s_waitcnt vmcnt(0)" ::: "memory");   // chunk c resident
    if (c + 1 < NCHUNK) stage(c + 1);
    const int buf = c & 1;
    const float* trp = s_tr + buf * (CH * 36);
    const float* ftp = s_ft + buf * (CH * 6);
    u32* prow = s_psi + (size_t)(c * 2) * 65;          // 2 windows per chunk
    float trA[8], ftA[8], trB[8], ftB[8];
    LOAD8(trA, ftA, 0);
#pragma unroll 1
    for (int g2 = 0; g2 < 14; g2 += 2) {
      u32* pqa = prow + ((g2 & 8) ? 65 : 0) + ((g2 * 8) & 63);
      STEPS8L(trA, ftA, pqa, trB, ftB, (g2 + 1) * 8);
      u32* pqb = prow + (((g2 + 1) & 8) ? 65 : 0) + (((g2 + 1) * 8) & 63);
      STEPS8L(trB, ftB, pqb, trA, ftA, (g2 + 2) * 8);
    }
    STEPS8L(trA, ftA, prow + 65 + 48, trB, ftB, 120);
    STEPS8(trB, ftB, prow + 65 + 56);
  }

  // ---- score + last_tag. Final step t=4095 is stepA -> layout1:
  // lane (g,l) holds delta_final[g]; groups 6,7 duplicate state 5 exactly.
  float sm = delta;
  sm = fmaxf(sm, dppf<0xB1>(sm));
  sm = fmaxf(sm, dppf<0x4E>(sm));
  sm = fmaxf(sm, dppf<0x141>(sm));
  sm = fmaxf(sm, dppf<0x128>(sm));
  sm = pl16max(sm);
  sm = pl32max(sm);
  u64 bs = __ballot(delta == sm);
  int last_tag = (int)((__builtin_ctzll(bs) >> 3) & 7);  // smallest g wins ties

  __syncthreads();  // all psi visible (single wave: waitcnt)

  // ---- per-segment backpointer-map composition (exact integer scan)
  const int u = lane;
  u32 Gm = 0u | (1u << 3) | (2u << 6) | (3u << 9) | (4u << 12) | (5u << 15);
#pragma unroll 1
  for (int k = 0; k < 64; ++k) {
    u32 p = s_psi[u * 65 + k];
    u32 ng = 0;
#pragma unroll
    for (int x = 0; x < 6; ++x) {
      u32 j = (p >> (3 * x)) & 7;
      u32 v = (Gm >> (3 * ((j < 6) ? j : 0))) & 7;  // clamp (p[0] dummy)
      ng |= v << (3 * x);
    }
    Gm = ng;
  }

  // ---- boundary-tag chain via readlane (uniform, register-only)
  int bcur = last_tag;
  int my_b = last_tag;  // lane 63
#pragma unroll 1
  for (int v = 63; v >= 1; --v) {
    u32 Gv = (u32)__builtin_amdgcn_readlane((int)Gm, v);
    bcur = (int)((Gv >> (3 * bcur)) & 7);
    my_b = (u == v - 1) ? bcur : my_b;
  }

  // ---- per-segment walk, emit path bytes
  {
    int tag = my_b;
    unsigned char* pb = (unsigned char*)s_path;
    pb[u * 64 + 63] = (unsigned char)tag;
#pragma unroll 1
    for (int k = 63; k >= 1; --k) {
      u32 p = s_psi[u * 65 + k];
      tag = (int)((p >> (3 * tag)) & 7);
      pb[u * 64 + k - 1] = (unsigned char)tag;
    }
  }
  if (lane == 0) out[b] = sm;
  __syncthreads();

  // ---- coalesced float path store
  float* outp = out + NB + (size_t)b * NT;
#pragma unroll
  for (int i = 0; i < (NT / 4) / 64; ++i) {
    u32 w = s_path[lane + i * 64];
    float4 f;
    f.x = (float)(w & 255u);
    f.y = (float)((w >> 8) & 255u);
    f.z = (float)((w >> 16) & 255u);
    f.w = (float)((w >> 24) & 255u);
    ((float4*)outp)[lane + i * 64] = f;
  }
}

extern "C" void kernel_launch(void* const* d_in, const int* in_sizes, int n_in,
                              void* d_out, int out_size, void* d_ws, size_t ws_size,
                              hipStream_t stream) {
  (void)in_sizes; (void)n_in; (void)out_size; (void)d_ws; (void)ws_size;
  const float* feats = (const float*)d_in[0];
  const float* trans = (const float*)d_in[1];
  float* out = (float*)d_out;
  hipLaunchKernelGGL(viterbi_k, dim3(NB), dim3(64), 0, stream, feats, trans, out);
}

// Round 12
// 444.718 us; speedup vs baseline: 1.1349x; 1.1349x over previous
//
#include <hip/hip_runtime.h>

#define NB 256
#define NT 4096
#define CH 32
#define NCHUNK (NT / CH)   // 128

typedef unsigned int u32;
typedef unsigned long long u64;
typedef int v2i __attribute__((ext_vector_type(2)));

typedef __attribute__((address_space(1))) const u32 gas_u32;
typedef __attribute__((address_space(3))) u32 las_u32;

__device__ __forceinline__ void gll16(const void* g, void* l) {
  __builtin_amdgcn_global_load_lds((gas_u32*)g, (las_u32*)l, 16, 0, 0);
}

template <int CTRL>
__device__ __forceinline__ float dppf(float x) {
  return __int_as_float(__builtin_amdgcn_update_dpp(
      0, __float_as_int(x), CTRL, 0xF, 0xF, true));
}

__device__ __forceinline__ float pl16max(float x) {
#if __has_builtin(__builtin_amdgcn_permlane16_swap)
  v2i r = __builtin_amdgcn_permlane16_swap(__float_as_int(x), __float_as_int(x),
                                           false, false);
  return fmaxf(__int_as_float(r[0]), __int_as_float(r[1]));
#else
  return fmaxf(x, __shfl_xor(x, 16, 64));
#endif
}

__device__ __forceinline__ float pl32max(float x) {
#if __has_builtin(__builtin_amdgcn_permlane32_swap)
  v2i r = __builtin_amdgcn_permlane32_swap(__float_as_int(x), __float_as_int(x),
                                           false, false);
  return fmaxf(__int_as_float(r[0]), __int_as_float(r[1]));
#else
  return fmaxf(x, __shfl_xor(x, 32, 64));
#endif
}

__global__ void __launch_bounds__(64, 1)
viterbi_k(const float* __restrict__ feats, const float* __restrict__ trans,
          float* __restrict__ out) {
  // LDS: tr 18432 + ft 3072 + psi 32768 + path 4096 = 58368 B (< 64KB)
  __shared__ __align__(16) float s_tr[2 * 2 * CH * 36];  // [bb][buf][1152]
  __shared__ __align__(16) float s_ft[2 * 2 * CH * 6];   // [bb][buf][192]
  __shared__ u32 s_psi[2 * NT];                          // [bb][4096] swizzled
  __shared__ u32 s_path[NT / 4];

  const int lane = (int)threadIdx.x;
  const int g = lane >> 3;
  const int l = lane & 7;
  const int gg = (g < 6) ? g : 5;  // clamp -> duplicate-of-5 invariant
  const int jj = (l < 6) ? l : 5;
  const int offTA = gg * 6 + jj;   // A-step (odd t): i=g, j=l
  const int offTB = jj * 6 + gg;   // B-step (even t): i=l, j=g
  const int offFA = gg;
  const int offFB = jj;

  const int b0 = blockIdx.x * 2, b1 = b0 + 1;
  const float* trb0 = trans + (size_t)b0 * NT * 36;
  const float* ftb0 = feats + (size_t)b0 * NT * 6;
  const float* trb1 = trans + (size_t)b1 * NT * 36;
  const float* ftb1 = feats + (size_t)b1 * NT * 6;

  // layout0: lane (g,l) holds delta[jj]; lanes l>=6 duplicate state 5.
  float d0 = (l == 4) ? 0.0f : -10000.0f;
  float d1 = d0;
  u32 mlo0 = 0, mhi0 = 0, mlo1 = 0, mhi1 = 0;

  auto stage = [&](int c) {
    const int buf = c & 1;
    {
      const float* gt = trb0 + (size_t)c * (CH * 36);   // 1152 floats
      float* lt = s_tr + buf * (CH * 36);
#pragma unroll
      for (int i = 0; i < 4; ++i) gll16(gt + i * 256 + lane * 4, lt + i * 256);
      if (lane < 32) gll16(gt + 1024 + lane * 4, lt + 1024);
      const float* gf = ftb0 + (size_t)c * (CH * 6);    // 192 floats
      float* lf = s_ft + buf * (CH * 6);
      if (lane < 48) gll16(gf + lane * 4, lf);
    }
    {
      const float* gt = trb1 + (size_t)c * (CH * 36);
      float* lt = s_tr + 2 * (CH * 36) + buf * (CH * 36);
#pragma unroll
      for (int i = 0; i < 4; ++i) gll16(gt + i * 256 + lane * 4, lt + i * 256);
      if (lane < 32) gll16(gt + 1024 + lane * 4, lt + 1024);
      const float* gf = ftb1 + (size_t)c * (CH * 6);
      float* lf = s_ft + 2 * (CH * 6) + buf * (CH * 6);
      if (lane < 48) gll16(gf + lane * 4, lf);
    }
  };

  // Two independent chains per step — compiler interleaves; chain 1 fills
  // chain 0's dependency-stall slots.
  auto stepA2 = [&](float t0, float f0, float t1, float f1, int slot) {
    float s0 = t0 + d0, s1 = t1 + d1;
    float m0 = fmaxf(s0, dppf<0xB1>(s0));
    float m1 = fmaxf(s1, dppf<0xB1>(s1));
    m0 = fmaxf(m0, dppf<0x4E>(m0));
    m1 = fmaxf(m1, dppf<0x4E>(m1));
    m0 = fmaxf(m0, dppf<0x141>(m0));
    m1 = fmaxf(m1, dppf<0x141>(m1));
    u64 a0 = __ballot(s0 == m0);            // bits at 8i+j
    u64 a1 = __ballot(s1 == m1);
    bool cap = (lane == slot);
    mlo0 = cap ? (u32)a0 : mlo0;  mhi0 = cap ? (u32)(a0 >> 32) : mhi0;
    mlo1 = cap ? (u32)a1 : mlo1;  mhi1 = cap ? (u32)(a1 >> 32) : mhi1;
    d0 = m0 + f0;  d1 = m1 + f1;
  };

  auto stepB2 = [&](float t0, float f0, float t1, float f1, int slot) {
    float s0 = t0 + d0, s1 = t1 + d1;
    float m0 = fmaxf(s0, dppf<0x128>(s0));  // xor8
    float m1 = fmaxf(s1, dppf<0x128>(s1));
    m0 = pl16max(m0);  m1 = pl16max(m1);
    m0 = pl32max(m0);  m1 = pl32max(m1);
    u64 a0 = __ballot(s0 == m0);            // bits at 8j+i
    u64 a1 = __ballot(s1 == m1);
    bool cap = (lane == slot);
    mlo0 = cap ? (u32)a0 : mlo0;  mhi0 = cap ? (u32)(a0 >> 32) : mhi0;
    mlo1 = cap ? (u32)a1 : mlo1;  mhi1 = cap ? (u32)(a1 >> 32) : mhi1;
    d0 = m0 + f0;  d1 = m1 + f1;
  };

  auto flushOne = [&](int base, u32 mlo, u32 mhi, u32* psib) {
    const u32 ub = (u32)(base >> 6) & 63;
    u32 pA = (u32)__builtin_ctz((mlo & 63u) | 64u);
    pA |= (u32)__builtin_ctz(((mlo >> 8) & 63u) | 64u) << 3;
    pA |= (u32)__builtin_ctz(((mlo >> 16) & 63u) | 64u) << 6;
    pA |= (u32)__builtin_ctz(((mlo >> 24) & 63u) | 64u) << 9;
    pA |= (u32)__builtin_ctz((mhi & 63u) | 64u) << 12;
    pA |= (u32)__builtin_ctz(((mhi >> 8) & 63u) | 64u) << 15;
    u64 bal = ((u64)mhi << 32) | (u64)mlo;
    u32 pB = 0;
#pragma unroll
    for (int i = 0; i < 6; ++i) {
      u64 mm = (bal >> i) & 0x0000010101010101ULL;
      u32 j = (u32)(__builtin_ctzll(mm | (1ULL << 48)) >> 3);
      pB |= j << (3 * i);
    }
    u32 p = (lane & 1) ? pA : pB;
    psib[base + (((u32)lane) ^ ub)] = p;   // bank-swizzled slot
  };

#define LOAD8x2(T0, F0, T1, F1, g8)                                           \
  {                                                                           \
    _Pragma("unroll") for (int q = 0; q < 8; ++q) {                           \
      T0[q] = trp0[((g8) + q) * 36 + ((q & 1) ? offTA : offTB)];              \
      F0[q] = ftp0[((g8) + q) * 6 + ((q & 1) ? offFA : offFB)];               \
      T1[q] = trp1[((g8) + q) * 36 + ((q & 1) ? offTA : offTB)];              \
      F1[q] = ftp1[((g8) + q) * 6 + ((q & 1) ? offFA : offFB)];               \
    }                                                                         \
  }

#define STEPS8x2(T0, F0, T1, F1, SB)                                          \
  {                                                                           \
    _Pragma("unroll") for (int q = 0; q < 8; ++q) {                           \
      if (q & 1) stepA2(T0[q], F0[q], T1[q], F1[q], (SB) + q);                \
      else       stepB2(T0[q], F0[q], T1[q], F1[q], (SB) + q);                \
    }                                                                         \
  }

#define STEPS8Lx2(T0, F0, T1, F1, SB, N0, G0, N1, G1, ng8)                    \
  {                                                                           \
    _Pragma("unroll") for (int q = 0; q < 8; ++q) {                           \
      if (q & 1) stepA2(T0[q], F0[q], T1[q], F1[q], (SB) + q);                \
      else       stepB2(T0[q], F0[q], T1[q], F1[q], (SB) + q);                \
      N0[q] = trp0[((ng8) + q) * 36 + ((q & 1) ? offTA : offTB)];             \
      G0[q] = ftp0[((ng8) + q) * 6 + ((q & 1) ? offFA : offFB)];              \
      N1[q] = trp1[((ng8) + q) * 36 + ((q & 1) ? offTA : offTB)];             \
      G1[q] = ftp1[((ng8) + q) * 6 + ((q & 1) ? offFA : offFB)];              \
    }                                                                         \
  }

  stage(0);
  asm volatile("s_waitcnt vmcnt(0)" ::: "memory");
  stage(1);

  // ---- chunk 0 (t = 0..31; t=0 skipped)
  {
    const float* trp0 = s_tr;
    const float* ftp0 = s_ft;
    const float* trp1 = s_tr + 2 * (CH * 36);
    const float* ftp1 = s_ft + 2 * (CH * 6);
    float tA0[8], fA0[8], tA1[8], fA1[8], tB0[8], fB0[8], tB1[8], fB1[8];
    LOAD8x2(tA0, fA0, tA1, fA1, 0);
    LOAD8x2(tB0, fB0, tB1, fB1, 8);
#pragma unroll
    for (int q = 1; q < 8; ++q) {
      if (q & 1) stepA2(tA0[q], fA0[q], tA1[q], fA1[q], q);
      else       stepB2(tA0[q], fA0[q], tA1[q], fA1[q], q);
    }
    STEPS8Lx2(tB0, fB0, tB1, fB1, 8, tA0, fA0, tA1, fA1, 16);
    STEPS8Lx2(tA0, fA0, tA1, fA1, 16, tB0, fB0, tB1, fB1, 24);
    STEPS8x2(tB0, fB0, tB1, fB1, 24);
  }

  // ---- chunks 1..127; flush after each odd chunk (window = 2 chunks)
#pragma unroll 1
  for (int c = 1; c < NCHUNK; ++c) {
    asm volatile("s_waitcnt vmcnt(0)" ::: "memory");   // chunk c resident
    if (c + 1 < NCHUNK) stage(c + 1);
    const int buf = c & 1;
    const float* trp0 = s_tr + buf * (CH * 36);
    const float* ftp0 = s_ft + buf * (CH * 6);
    const float* trp1 = s_tr + 2 * (CH * 36) + buf * (CH * 36);
    const float* ftp1 = s_ft + 2 * (CH * 6) + buf * (CH * 6);
    const int sb = (c & 1) * 32;   // slot base within 64-step window
    float tA0[8], fA0[8], tA1[8], fA1[8], tB0[8], fB0[8], tB1[8], fB1[8];
    LOAD8x2(tA0, fA0, tA1, fA1, 0);
    STEPS8Lx2(tA0, fA0, tA1, fA1, sb, tB0, fB0, tB1, fB1, 8);
    STEPS8Lx2(tB0, fB0, tB1, fB1, sb + 8, tA0, fA0, tA1, fA1, 16);
    STEPS8Lx2(tA0, fA0, tA1, fA1, sb + 16, tB0, fB0, tB1, fB1, 24);
    STEPS8x2(tB0, fB0, tB1, fB1, sb + 24);
    if (c & 1) {
      const int base = (c >> 1) * 64;
      flushOne(base, mlo0, mhi0, s_psi);
      flushOne(base, mlo1, mhi1, s_psi + NT);
    }
  }

  // ---- scores + last tags (final step t=4095 is stepA -> layout1)
  float sm0, sm1;
  int last0, last1;
  {
    float sm = d0;
    sm = fmaxf(sm, dppf<0xB1>(sm));
    sm = fmaxf(sm, dppf<0x4E>(sm));
    sm = fmaxf(sm, dppf<0x141>(sm));
    sm = fmaxf(sm, dppf<0x128>(sm));
    sm = pl16max(sm);
    sm = pl32max(sm);
    u64 bs = __ballot(d0 == sm);
    last0 = (int)((__builtin_ctzll(bs) >> 3) & 7);
    sm0 = sm;
  }
  {
    float sm = d1;
    sm = fmaxf(sm, dppf<0xB1>(sm));
    sm = fmaxf(sm, dppf<0x4E>(sm));
    sm = fmaxf(sm, dppf<0x141>(sm));
    sm = fmaxf(sm, dppf<0x128>(sm));
    sm = pl16max(sm);
    sm = pl32max(sm);
    u64 bs = __ballot(d1 == sm);
    last1 = (int)((__builtin_ctzll(bs) >> 3) & 7);
    sm1 = sm;
  }
  if (lane == 0) { out[b0] = sm0; out[b1] = sm1; }

  // ---- backtrack per batch (sequential; off critical path)
  const int u = lane;
#pragma unroll 1
  for (int bb = 0; bb < 2; ++bb) {
    u32* psib = s_psi + bb * NT;
    int last_tag = bb ? last1 : last0;
    __syncthreads();  // psi writes visible / s_path reusable

    u32 Gm = 0u | (1u << 3) | (2u << 6) | (3u << 9) | (4u << 12) | (5u << 15);
#pragma unroll 1
    for (int k = 0; k < 64; ++k) {
      u32 p = psib[u * 64 + (k ^ u)];
      u32 ng = 0;
#pragma unroll
      for (int x = 0; x < 6; ++x) {
        u32 j = (p >> (3 * x)) & 7;
        u32 v = (Gm >> (3 * ((j < 6) ? j : 0))) & 7;  // clamp (psi[0] dummy)
        ng |= v << (3 * x);
      }
      Gm = ng;
    }

    int bcur = last_tag;
    int my_b = last_tag;  // lane 63
#pragma unroll 1
    for (int v = 63; v >= 1; --v) {
      u32 Gv = (u32)__builtin_amdgcn_readlane((int)Gm, v);
      bcur = (int)((Gv >> (3 * bcur)) & 7);
      my_b = (u == v - 1) ? bcur : my_b;
    }

    {
      int tag = my_b;
      unsigned char* pb = (unsigned char*)s_path;
      pb[u * 64 + 63] = (unsigned char)tag;
#pragma unroll 1
      for (int k = 63; k >= 1; --k) {
        u32 p = psib[u * 64 + (k ^ u)];
        tag = (int)((p >> (3 * tag)) & 7);
        pb[u * 64 + k - 1] = (unsigned char)tag;
      }
    }
    __syncthreads();

    float* outp = out + NB + (size_t)(bb ? b1 : b0) * NT;
#pragma unroll
    for (int i = 0; i < (NT / 4) / 64; ++i) {
      u32 w = s_path[lane + i * 64];
      float4 f;
      f.x = (float)(w & 255u);
      f.y = (float)((w >> 8) & 255u);
      f.z = (float)((w >> 16) & 255u);
      f.w = (float)((w >> 24) & 255u);
      ((float4*)outp)[lane + i * 64] = f;
    }
  }
}

extern "C" void kernel_launch(void* const* d_in, const int* in_sizes, int n_in,
                              void* d_out, int out_size, void* d_ws, size_t ws_size,
                              hipStream_t stream) {
  (void)in_sizes; (void)n_in; (void)out_size; (void)d_ws; (void)ws_size;
  const float* feats = (const float*)d_in[0];
  const float* trans = (const float*)d_in[1];
  float* out = (float*)d_out;
  hipLaunchKernelGGL(viterbi_k, dim3(NB / 2), dim3(64), 0, stream,
                     feats, trans, out);
}